// Round 2
// baseline (387.268 us; speedup 1.0000x reference)
//
#include <hip/hip_runtime.h>
#include <hip/hip_bf16.h>

// ---- problem constants ----
#define DB   2
#define DS   2048
#define DH   2048
#define DNH  32
#define DKVH 8
#define DHD  64
#define DM   4096    // B*S
#define DNQKV 3072   // NH*HD + 2*KVH*HD

typedef __attribute__((ext_vector_type(8))) short bf16x8;
typedef __attribute__((ext_vector_type(4))) float f32x4;
typedef __attribute__((ext_vector_type(8))) unsigned short us8;
typedef __attribute__((ext_vector_type(4))) unsigned short us4;
typedef __attribute__((ext_vector_type(2))) unsigned int u32x2;

__device__ __forceinline__ float b2f(unsigned short u) {
  unsigned int x = ((unsigned int)u) << 16;
  return __builtin_bit_cast(float, x);
}
__device__ __forceinline__ unsigned short f2b(float f) {
  unsigned int u = __builtin_bit_cast(unsigned int, f);
  return (unsigned short)((u + 0x8000u) >> 16);
}
__device__ __forceinline__ unsigned int cvt_pk_bf16(float lo, float hi) {
  unsigned int r;
  asm("v_cvt_pk_bf16_f32 %0, %1, %2" : "=v"(r) : "v"(lo), "v"(hi));
  return r;
}
__device__ __forceinline__ void async_copy16(void* lds, const void* g) {
  __builtin_amdgcn_global_load_lds((const __attribute__((address_space(1))) void*)g,
                                   (__attribute__((address_space(3))) void*)lds,
                                   16, 0, 0);
}

// raw barrier (no waitcnt drain) + compiler memory fences
#define BARRIER() do { asm volatile("" ::: "memory"); __builtin_amdgcn_s_barrier(); asm volatile("" ::: "memory"); } while (0)
#define LGKM0()   asm volatile("s_waitcnt lgkmcnt(0)" ::: "memory")
#define WAITVM(n) asm volatile("s_waitcnt vmcnt(" #n ")" ::: "memory")
#define MFMA16(d, a, bb) (d) = __builtin_amdgcn_mfma_f32_16x16x32_bf16((a), (bb), (d), 0, 0, 0)

// ---- dtype detector ----
__global__ void detect_mode(const unsigned short* __restrict__ w, int* __restrict__ flags) {
  int t = threadIdx.x;
  int trips = 0;
  for (int i = 0; i < 4; i++) {
    unsigned short u = w[t * 4 + i];
    int e = (u >> 7) & 0xFF;
    if (e >= 161 || (e <= 93 && e != 0)) trips++;
  }
  for (int off = 32; off > 0; off >>= 1) trips += __shfl_down(trips, off);
  if (t == 0) flags[0] = (trips >= 8) ? 1 : 0;  // 1 = fp32 I/O, 0 = bf16
}

// ---- X -> bf16 ----
__global__ __launch_bounds__(256) void convert_x(const void* __restrict__ xin,
                                                 unsigned short* __restrict__ xb,
                                                 const int* __restrict__ flags, int n) {
  int mode = flags[0];
  int i = (blockIdx.x * 256 + threadIdx.x) * 8;
  if (i >= n) return;
  if (mode) {
    const float* f = (const float*)xin;
    us8 o;
#pragma unroll
    for (int j = 0; j < 8; j++) o[j] = f2b(f[i + j]);
    *(us8*)&xb[i] = o;
  } else {
    *(us8*)&xb[i] = *(const us8*)((const unsigned short*)xin + i);
  }
}

// ---- W [R][C] -> bf16 W^T [C][R] ----
__global__ __launch_bounds__(256) void transpose_w(const void* __restrict__ win,
                                                   unsigned short* __restrict__ out,
                                                   const int* __restrict__ flags,
                                                   int R, int C) {
  __shared__ float tile[32][33];
  int mode = flags[0];
  int c0 = blockIdx.x * 32, r0 = blockIdx.y * 32;
  int tx = threadIdx.x & 31, ty = threadIdx.x >> 5;
  if (mode) {
    const float* f = (const float*)win;
    for (int i = ty; i < 32; i += 8) tile[i][tx] = f[(size_t)(r0 + i) * C + c0 + tx];
  } else {
    const unsigned short* bsrc = (const unsigned short*)win;
    for (int i = ty; i < 32; i += 8) tile[i][tx] = b2f(bsrc[(size_t)(r0 + i) * C + c0 + tx]);
  }
  __syncthreads();
  for (int i = ty; i < 32; i += 8) out[(size_t)(c0 + i) * R + r0 + tx] = f2b(tile[tx][i]);
}

#define QSC 0.18033688011112042f   // (1/8) * log2(e)

// ============================================================================
// 8-phase 256x256 QKV GEMM + RoPE + head-major scatter. (unchanged, round-1)
// ============================================================================
__global__ __launch_bounds__(512, 2)
void gemm_qkv(const unsigned short* __restrict__ A, const unsigned short* __restrict__ Bt,
              const int* __restrict__ pos_ids,
              unsigned short* __restrict__ qws, unsigned short* __restrict__ kws,
              unsigned short* __restrict__ vt) {
  __shared__ __align__(16) unsigned short sm[65536];  // 128 KiB
  int tid = threadIdx.x, lane = tid & 63, wave = tid >> 6;
  int wm = wave >> 2, wn = wave & 3;           // 2 x 4 waves, wave tile 128x64
  int quad = lane >> 4, l15 = lane & 15;

  int bid = blockIdx.x;                         // 192 blocks, 192 % 8 == 0
  int wg = (bid & 7) * 24 + (bid >> 3);         // XCD-contiguous chunks of 24
  int ty = wg / 12, tx = wg - ty * 12;
  size_t tm0 = (size_t)ty * 256, tn0 = (size_t)tx * 256;

  const unsigned short* Ab = A + tm0 * 2048;
  const unsigned short* Bb = Bt + tn0 * 2048;

  auto UA = [&](int bu, int kh) { return sm + (bu * 2 + kh) * 8192; };
  auto UB = [&](int bu, int kh) { return sm + 32768 + (bu * 2 + kh) * 8192; };

  int c0 = tid, c1 = tid + 512;
  int r0s = c0 >> 2, r1s = c1 >> 2;
  int cc0 = (c0 & 3) ^ ((r0s >> 1) & 3);
  int cc1 = (c1 & 3) ^ ((r1s >> 1) & 3);
  size_t ga0 = (size_t)r0s * 2048 + cc0 * 8;
  size_t ga1 = (size_t)r1s * 2048 + cc1 * 8;

  auto stA = [&](int t, int kh, int bu) {
    const unsigned short* s = Ab + (size_t)t * 64 + kh * 32;
    async_copy16(UA(bu, kh) + c0 * 8, s + ga0);
    async_copy16(UA(bu, kh) + c1 * 8, s + ga1);
  };
  auto stB = [&](int t, int kh, int bu) {
    const unsigned short* s = Bb + (size_t)t * 64 + kh * 32;
    async_copy16(UB(bu, kh) + c0 * 8, s + ga0);
    async_copy16(UB(bu, kh) + c1 * 8, s + ga1);
  };

  int rdoff = l15 * 32 + ((quad << 3) ^ (((l15 >> 1) & 3) << 3));

  f32x4 zero4 = {0.f, 0.f, 0.f, 0.f};
  f32x4 acc[8][4];
#pragma unroll
  for (int mi = 0; mi < 8; mi++)
#pragma unroll
    for (int ni = 0; ni < 4; ni++) acc[mi][ni] = zero4;

  stA(0, 0, 0); stB(0, 0, 0); stA(0, 1, 0); stB(0, 1, 0); stA(1, 0, 1); stB(1, 0, 1);
  WAITVM(8); BARRIER();

#pragma unroll 2
  for (int t = 0; t < 32; ++t) {
    int bu = t & 1, bn = bu ^ 1;
    int t1 = (t + 1 < 32) ? t + 1 : 31;
    int t2 = (t + 2 < 32) ? t + 2 : 31;
    bf16x8 af[8];
    const unsigned short* pA0 = UA(bu, 0) + wm * 4096 + rdoff;
    const unsigned short* pB0 = UB(bu, 0) + wn * 2048 + rdoff;
    const unsigned short* pA1 = UA(bu, 1) + wm * 4096 + rdoff;
    const unsigned short* pB1 = UB(bu, 1) + wn * 2048 + rdoff;

    // p0
#pragma unroll
    for (int mi = 0; mi < 8; mi++) af[mi] = *(const bf16x8*)(pA0 + mi * 512);
    bf16x8 b0 = *(const bf16x8*)pB0;
    bf16x8 b1 = *(const bf16x8*)(pB0 + 512);
    stA(t1, 1, bn);
    BARRIER(); LGKM0();
    __builtin_amdgcn_s_setprio(1);
#pragma unroll
    for (int mi = 0; mi < 8; mi++) { MFMA16(acc[mi][0], af[mi], b0); MFMA16(acc[mi][1], af[mi], b1); }
    __builtin_amdgcn_s_setprio(0);
    BARRIER();

    // p1
    bf16x8 b2 = *(const bf16x8*)(pB0 + 1024);
    bf16x8 b3 = *(const bf16x8*)(pB0 + 1536);
    stB(t1, 1, bn);
    BARRIER(); LGKM0();
    __builtin_amdgcn_s_setprio(1);
#pragma unroll
    for (int mi = 0; mi < 8; mi++) { MFMA16(acc[mi][2], af[mi], b2); MFMA16(acc[mi][3], af[mi], b3); }
    __builtin_amdgcn_s_setprio(0);
    WAITVM(8);
    BARRIER();

    // p2
#pragma unroll
    for (int mi = 0; mi < 8; mi++) af[mi] = *(const bf16x8*)(pA1 + mi * 512);
    b0 = *(const bf16x8*)pB1;
    b1 = *(const bf16x8*)(pB1 + 512);
    stA(t2, 0, bu);
    BARRIER(); LGKM0();
    __builtin_amdgcn_s_setprio(1);
#pragma unroll
    for (int mi = 0; mi < 8; mi++) { MFMA16(acc[mi][0], af[mi], b0); MFMA16(acc[mi][1], af[mi], b1); }
    __builtin_amdgcn_s_setprio(0);
    BARRIER();

    // p3
    b2 = *(const bf16x8*)(pB1 + 1024);
    b3 = *(const bf16x8*)(pB1 + 1536);
    stB(t2, 0, bu);
    BARRIER(); LGKM0();
    __builtin_amdgcn_s_setprio(1);
#pragma unroll
    for (int mi = 0; mi < 8; mi++) { MFMA16(acc[mi][2], af[mi], b2); MFMA16(acc[mi][3], af[mi], b3); }
    __builtin_amdgcn_s_setprio(0);
    WAITVM(8);
    BARRIER();
  }
  WAITVM(0);

  // ---- epilogue: RoPE for Q/K slots, transposed scatter for V ----
  int hs = (int)(tn0 >> 6) + wn;
  if (hs < 40) {
    float sc = (hs < 32) ? QSC : 1.0f;
    unsigned short* dst0 = (hs < 32) ? qws : kws;
    int hh = (hs < 32) ? hs : (hs - 32);
    float invf0 = __expf(-(float)l15 * (9.210340371976184f / 32.0f));
    float invf1 = invf0 * 0.01f;
#pragma unroll
    for (int mi = 0; mi < 8; mi++)
#pragma unroll
      for (int r = 0; r < 4; r++) {
        size_t gr = tm0 + wm * 128 + mi * 16 + quad * 4 + r;
        int bb = (int)(gr >> 11), s = (int)(gr & 2047);
        float tpos = (float)pos_ids[gr];
        unsigned short* row = dst0 + ((size_t)(bb * ((hs < 32) ? DNH : DKVH) + hh) * DS + s) * DHD;
#pragma unroll
        for (int ni = 0; ni < 2; ni++) {
          float x1 = acc[mi][ni][r], x2 = acc[mi][ni + 2][r];
          float ang = tpos * (ni ? invf1 : invf0);
          float sn, cs;
          __sincosf(ang, &sn, &cs);
          int d = ni * 16 + l15;
          row[d]      = f2b((x1 * cs - x2 * sn) * sc);
          row[d + 32] = f2b((x2 * cs + x1 * sn) * sc);
        }
      }
  } else {
    int vh = hs - 40;
    int bb = (int)(tm0 >> 11);
    int s0 = (int)(tm0 & 2047) + wm * 128 + quad * 4;
#pragma unroll
    for (int mi = 0; mi < 8; mi++)
#pragma unroll
      for (int ni = 0; ni < 4; ni++) {
        int d = ni * 16 + l15;
        us4 o4;
#pragma unroll
        for (int r = 0; r < 4; r++) o4[r] = f2b(acc[mi][ni][r]);
        *(us4*)&vt[((size_t)(bb * DKVH + vh) * DHD + d) * DS + s0 + mi * 16] = o4;
      }
  }
}

// ============================================================================
// 8-phase 128x256 out GEMM (unchanged, round-1)
// ============================================================================
__global__ __launch_bounds__(512, 2)
void gemm_out(const unsigned short* __restrict__ A, const unsigned short* __restrict__ Bt,
              unsigned short* __restrict__ Cb, float* __restrict__ Cf,
              const int* __restrict__ outmode) {
  __shared__ __align__(16) unsigned short sm[49152];  // 96 KiB
  int tid = threadIdx.x, lane = tid & 63, wave = tid >> 6;
  int wm = wave >> 2, wn = wave & 3;
  int quad = lane >> 4, l15 = lane & 15;

  int bid = blockIdx.x;
  int wg = (bid & 7) * 32 + (bid >> 3);
  int ty = wg >> 3, tx = wg & 7;
  size_t tm0 = (size_t)ty * 128, tn0 = (size_t)tx * 256;

  const unsigned short* Ab = A + tm0 * 2048;
  const unsigned short* Bb = Bt + tn0 * 2048;

  auto UA = [&](int bu, int kh) { return sm + (bu * 2 + kh) * 4096; };
  auto UB = [&](int bu, int kh) { return sm + 16384 + (bu * 2 + kh) * 8192; };

  int c0 = tid, c1 = tid + 512;
  int r0s = c0 >> 2, r1s = c1 >> 2;
  int cc0 = (c0 & 3) ^ ((r0s >> 1) & 3);
  int cc1 = (c1 & 3) ^ ((r1s >> 1) & 3);
  size_t ga0 = (size_t)r0s * 2048 + cc0 * 8;
  size_t ga1 = (size_t)r1s * 2048 + cc1 * 8;

  auto stA = [&](int t, int kh, int bu) {
    const unsigned short* s = Ab + (size_t)t * 64 + kh * 32;
    async_copy16(UA(bu, kh) + c0 * 8, s + ga0);
  };
  auto stB = [&](int t, int kh, int bu) {
    const unsigned short* s = Bb + (size_t)t * 64 + kh * 32;
    async_copy16(UB(bu, kh) + c0 * 8, s + ga0);
    async_copy16(UB(bu, kh) + c1 * 8, s + ga1);
  };

  int rdoff = l15 * 32 + ((quad << 3) ^ (((l15 >> 1) & 3) << 3));

  f32x4 zero4 = {0.f, 0.f, 0.f, 0.f};
  f32x4 acc[4][4];
#pragma unroll
  for (int mi = 0; mi < 4; mi++)
#pragma unroll
    for (int ni = 0; ni < 4; ni++) acc[mi][ni] = zero4;

  stA(0, 0, 0); stB(0, 0, 0); stA(0, 1, 0); stB(0, 1, 0); stA(1, 0, 1); stB(1, 0, 1);
  WAITVM(6); BARRIER();

#pragma unroll 2
  for (int t = 0; t < 32; ++t) {
    int bu = t & 1, bn = bu ^ 1;
    int t1 = (t + 1 < 32) ? t + 1 : 31;
    int t2 = (t + 2 < 32) ? t + 2 : 31;
    bf16x8 af[4];
    const unsigned short* pA0 = UA(bu, 0) + wm * 2048 + rdoff;
    const unsigned short* pB0 = UB(bu, 0) + wn * 2048 + rdoff;
    const unsigned short* pA1 = UA(bu, 1) + wm * 2048 + rdoff;
    const unsigned short* pB1 = UB(bu, 1) + wn * 2048 + rdoff;

    // p0
#pragma unroll
    for (int mi = 0; mi < 4; mi++) af[mi] = *(const bf16x8*)(pA0 + mi * 512);
    bf16x8 b0 = *(const bf16x8*)pB0;
    bf16x8 b1 = *(const bf16x8*)(pB0 + 512);
    stA(t1, 1, bn);
    BARRIER(); LGKM0();
    __builtin_amdgcn_s_setprio(1);
#pragma unroll
    for (int mi = 0; mi < 4; mi++) { MFMA16(acc[mi][0], af[mi], b0); MFMA16(acc[mi][1], af[mi], b1); }
    __builtin_amdgcn_s_setprio(0);
    BARRIER();

    // p1
    bf16x8 b2 = *(const bf16x8*)(pB0 + 1024);
    bf16x8 b3 = *(const bf16x8*)(pB0 + 1536);
    stB(t1, 1, bn);
    BARRIER(); LGKM0();
    __builtin_amdgcn_s_setprio(1);
#pragma unroll
    for (int mi = 0; mi < 4; mi++) { MFMA16(acc[mi][2], af[mi], b2); MFMA16(acc[mi][3], af[mi], b3); }
    __builtin_amdgcn_s_setprio(0);
    WAITVM(6);
    BARRIER();

    // p2
#pragma unroll
    for (int mi = 0; mi < 4; mi++) af[mi] = *(const bf16x8*)(pA1 + mi * 512);
    b0 = *(const bf16x8*)pB1;
    b1 = *(const bf16x8*)(pB1 + 512);
    stA(t2, 0, bu);
    BARRIER(); LGKM0();
    __builtin_amdgcn_s_setprio(1);
#pragma unroll
    for (int mi = 0; mi < 4; mi++) { MFMA16(acc[mi][0], af[mi], b0); MFMA16(acc[mi][1], af[mi], b1); }
    __builtin_amdgcn_s_setprio(0);
    BARRIER();

    // p3
    b2 = *(const bf16x8*)(pB1 + 1024);
    b3 = *(const bf16x8*)(pB1 + 1536);
    stB(t2, 0, bu);
    BARRIER(); LGKM0();
    __builtin_amdgcn_s_setprio(1);
#pragma unroll
    for (int mi = 0; mi < 4; mi++) { MFMA16(acc[mi][2], af[mi], b2); MFMA16(acc[mi][3], af[mi], b3); }
    __builtin_amdgcn_s_setprio(0);
    WAITVM(6);
    BARRIER();
  }
  WAITVM(0);

  int mode = *outmode;
#pragma unroll
  for (int mi = 0; mi < 4; mi++)
#pragma unroll
    for (int ni = 0; ni < 4; ni++)
#pragma unroll
      for (int r = 0; r < 4; r++) {
        size_t gr = tm0 + wm * 64 + mi * 16 + quad * 4 + r;
        size_t gc = tn0 + wn * 64 + ni * 16 + l15;
        float v = acc[mi][ni][r];
        if (mode) Cf[gr * 2048 + gc] = v;
        else      Cb[gr * 2048 + gc] = f2b(v);
      }
}

// ============================================================================
// causal GQA flash attention v2:
//  - K LDS XOR-swizzled (T2: inverse-swz source + swz read) -> 2-way max
//  - K double-buffered, prefetch issued BEFORE compute, one WAITVM(0)+barrier
//    per tile (latency hidden under QK^T+softmax+PV)
//  - V read directly from global as B-fragments (vt is [d][s]; LDS stage was a
//    pure round-trip; KV is L2-resident)  [common-mistake #7]
//  - defer-max rescale skip (T13, THR=8 in log2 units)
//  - v_cvt_pk_bf16_f32 for P and O packing
// ============================================================================
__global__ __launch_bounds__(256, 4)
void flash_attn(const unsigned short* __restrict__ q, const unsigned short* __restrict__ k,
                const unsigned short* __restrict__ vt, unsigned short* __restrict__ ctx) {
  __shared__ __align__(16) unsigned short lK[2][2][64 * 32];  // [buf][half]
  __shared__ __align__(16) unsigned short lP[4 * 16 * 72];
  int tid = threadIdx.x, lane = tid & 63, wave = tid >> 6;
  int quad = lane >> 4, l15 = lane & 15;
  int bh = blockIdx.y, b = bh >> 5, h = bh & 31, kvh = h >> 2;
  const unsigned short* qb = q + (size_t)(b * DNH + h) * DS * DHD;
  const unsigned short* kb = k + (size_t)(b * DKVH + kvh) * DS * DHD;
  const unsigned short* vb = vt + (size_t)(b * DKVH + kvh) * DHD * DS;
  unsigned short* lPw = lP + wave * 16 * 72;
  int r4 = tid >> 2;
  int cc8 = ((tid & 3) ^ ((r4 >> 1) & 3)) * 8;   // inverse-swizzled source chunk
  int swz = ((l15 >> 1) & 3) << 3;               // read-side XOR (shorts)

  f32x4 zero4 = {0.f, 0.f, 0.f, 0.f};
  for (int ph = 0; ph < 2; ph++) {
    int qt = ph ? (31 - blockIdx.x) : blockIdx.x;
    int q0 = qt * 64;
    const unsigned short* qp = qb + (size_t)(q0 + wave * 16 + l15) * DHD + quad * 8;
    bf16x8 qf0 = *(const bf16x8*)qp;
    bf16x8 qf1 = *(const bf16x8*)(qp + 32);
    f32x4 oacc[4];
#pragma unroll
    for (int dj = 0; dj < 4; dj++) oacc[dj] = zero4;
    float mrow = -1e30f, lrow = 0.f;

    int nt = qt + 1;
    // prologue: stage tile 0 -> buf 0
    {
      const unsigned short* s = kb + (size_t)r4 * DHD + cc8;
      async_copy16(&lK[0][0][tid * 8], s);
      async_copy16(&lK[0][1][tid * 8], s + 32);
    }
    WAITVM(0); BARRIER();

    int cur = 0;
    for (int t = 0; t < nt; t++) {
      int kv0 = t * 64;
      // prefetch next K tile into other buffer (issued before compute)
      if (t + 1 < nt) {
        const unsigned short* s = kb + (size_t)(kv0 + 64 + r4) * DHD + cc8;
        async_copy16(&lK[cur ^ 1][0][tid * 8], s);
        async_copy16(&lK[cur ^ 1][1][tid * 8], s + 32);
      }
      // QK^T from swizzled LDS
      f32x4 sacc[4];
#pragma unroll
      for (int nj = 0; nj < 4; nj++) {
        int ro = (nj * 16 + l15) * 32 + ((quad * 8) ^ swz);
        bf16x8 kf0 = *(const bf16x8*)&lK[cur][0][ro];
        bf16x8 kf1 = *(const bf16x8*)&lK[cur][1][ro];
        sacc[nj] = zero4;
        MFMA16(sacc[nj], kf0, qf0);
        MFMA16(sacc[nj], kf1, qf1);
      }
      // V fragments direct from global (L2-resident); issued early, used after softmax
      bf16x8 vf0[4], vf1[4];
#pragma unroll
      for (int dj = 0; dj < 4; dj++) {
        const unsigned short* vp = vb + (size_t)(dj * 16 + l15) * DS + kv0 + quad * 8;
        vf0[dj] = *(const bf16x8*)vp;
        vf1[dj] = *(const bf16x8*)(vp + 32);
      }
      if (t == nt - 1) {
        int ql = wave * 16 + l15;
#pragma unroll
        for (int nj = 0; nj < 4; nj++)
#pragma unroll
          for (int r = 0; r < 4; r++)
            if (nj * 16 + quad * 4 + r > ql) sacc[nj][r] = -1e30f;
      }
      // row max (max3-friendly triples)
      float a0 = fmaxf(fmaxf(sacc[0][0], sacc[0][1]), sacc[0][2]);
      float a1 = fmaxf(fmaxf(sacc[0][3], sacc[1][0]), sacc[1][1]);
      float a2 = fmaxf(fmaxf(sacc[1][2], sacc[1][3]), sacc[2][0]);
      float a3 = fmaxf(fmaxf(sacc[2][1], sacc[2][2]), sacc[2][3]);
      float a4 = fmaxf(fmaxf(sacc[3][0], sacc[3][1]), sacc[3][2]);
      float tm = fmaxf(fmaxf(fmaxf(a0, a1), fmaxf(a2, a3)), fmaxf(a4, sacc[3][3]));
      tm = fmaxf(tm, __shfl_xor(tm, 16));
      tm = fmaxf(tm, __shfl_xor(tm, 32));
      // defer-max: only rescale when the running max grew by > 8 (log2 units)
      if (!__all(tm <= mrow + 8.f)) {
        float mn = fmaxf(mrow, tm);
        float alpha = __builtin_amdgcn_exp2f(mrow - mn);
        mrow = mn;
        lrow *= alpha;
#pragma unroll
        for (int dj = 0; dj < 4; dj++)
#pragma unroll
          for (int r = 0; r < 4; r++) oacc[dj][r] *= alpha;
      }
      float rs = 0.f;
#pragma unroll
      for (int nj = 0; nj < 4; nj++)
#pragma unroll
        for (int r = 0; r < 4; r++) {
          float e = __builtin_amdgcn_exp2f(sacc[nj][r] - mrow);
          sacc[nj][r] = e;
          rs += e;
        }
      rs += __shfl_xor(rs, 16);
      rs += __shfl_xor(rs, 32);
      lrow += rs;
      // pack P -> LDS (per-wave buffer) via cvt_pk
#pragma unroll
      for (int nj = 0; nj < 4; nj++) {
        u32x2 w2;
        w2[0] = cvt_pk_bf16(sacc[nj][0], sacc[nj][1]);
        w2[1] = cvt_pk_bf16(sacc[nj][2], sacc[nj][3]);
        *(u32x2*)&lPw[l15 * 72 + nj * 16 + quad * 4] = w2;
      }
      bf16x8 pf0 = *(const bf16x8*)&lPw[l15 * 72 + quad * 8];
      bf16x8 pf1 = *(const bf16x8*)&lPw[l15 * 72 + 32 + quad * 8];
#pragma unroll
      for (int dj = 0; dj < 4; dj++) {
        MFMA16(oacc[dj], vf0[dj], pf0);
        MFMA16(oacc[dj], vf1[dj], pf1);
      }
      WAITVM(0); BARRIER();   // prefetch landed long ago; all waves done with buf
      cur ^= 1;
    }
    float inv = __builtin_amdgcn_rcpf(lrow);
    size_t orow = ((size_t)b * DS + q0 + wave * 16 + l15) * (DNH * DHD) + (size_t)h * DHD;
#pragma unroll
    for (int dj = 0; dj < 4; dj++) {
      u32x2 o2;
      o2[0] = cvt_pk_bf16(oacc[dj][0] * inv, oacc[dj][1] * inv);
      o2[1] = cvt_pk_bf16(oacc[dj][2] * inv, oacc[dj][3] * inv);
      *(u32x2*)&ctx[orow + dj * 16 + quad * 4] = o2;
    }
  }
}

extern "C" void kernel_launch(void* const* d_in, const int* in_sizes, int n_in,
                              void* d_out, int out_size, void* d_ws, size_t ws_size,
                              hipStream_t stream) {
  (void)in_sizes; (void)n_in; (void)out_size; (void)ws_size;
  const void* hs = d_in[0];
  const int* pos = (const int*)d_in[2];
  const void* wq = d_in[3];
  const void* wk = d_in[4];
  const void* wv = d_in[5];
  const void* wo = d_in[6];

  char* ws = (char*)d_ws;
  size_t off = 0;
  auto take = [&](size_t bytes) -> char* {
    char* p = ws + off;
    off += (bytes + 255) & ~(size_t)255;
    return p;
  };
  int* flags            = (int*)take(256);
  unsigned short* xb    = (unsigned short*)take((size_t)DM * DH * 2);
  unsigned short* wtqkv = (unsigned short*)take((size_t)DNQKV * DH * 2);
  unsigned short* wto   = (unsigned short*)take((size_t)DH * DH * 2);
  unsigned short* qws   = (unsigned short*)take((size_t)DB * DNH * DS * DHD * 2);
  unsigned short* kws   = (unsigned short*)take((size_t)DB * DKVH * DS * DHD * 2);
  unsigned short* vtws  = (unsigned short*)take((size_t)DB * DKVH * DS * DHD * 2);
  unsigned short* ctx   = (unsigned short*)take((size_t)DM * DNH * DHD * 2);

  detect_mode<<<1, 64, 0, stream>>>((const unsigned short*)wq, flags);
  convert_x<<<DM * DH / 8 / 256, 256, 0, stream>>>(hs, xb, flags, DM * DH);
  transpose_w<<<dim3(64, 64), 256, 0, stream>>>(wq, wtqkv, flags, 2048, 2048);
  transpose_w<<<dim3(16, 64), 256, 0, stream>>>(wk, wtqkv + (size_t)2048 * 2048, flags, 2048, 512);
  transpose_w<<<dim3(16, 64), 256, 0, stream>>>(wv, wtqkv + (size_t)2560 * 2048, flags, 2048, 512);
  transpose_w<<<dim3(64, 64), 256, 0, stream>>>(wo, wto, flags, 2048, 2048);

  gemm_qkv<<<dim3(192), 512, 0, stream>>>(xb, wtqkv, pos, qws, kws, vtws);

  flash_attn<<<dim3(16, DB * DNH), 256, 0, stream>>>(qws, kws, vtws, ctx);

  gemm_out<<<dim3(256), 512, 0, stream>>>(ctx, wto, (unsigned short*)d_out, (float*)d_out, flags);
}

// Round 3
// 318.697 us; speedup vs baseline: 1.2152x; 1.2152x over previous
//
#include <hip/hip_runtime.h>
#include <hip/hip_bf16.h>

// ---- problem constants ----
#define DB   2
#define DS   2048
#define DH   2048
#define DNH  32
#define DKVH 8
#define DHD  64
#define DM   4096    // B*S
#define DNQKV 3072   // NH*HD + 2*KVH*HD

typedef __attribute__((ext_vector_type(8))) short bf16x8;
typedef __attribute__((ext_vector_type(4))) float f32x4;
typedef __attribute__((ext_vector_type(8))) unsigned short us8;
typedef __attribute__((ext_vector_type(4))) unsigned short us4;
typedef __attribute__((ext_vector_type(2))) unsigned int u32x2;

__device__ __forceinline__ float b2f(unsigned short u) {
  unsigned int x = ((unsigned int)u) << 16;
  return __builtin_bit_cast(float, x);
}
__device__ __forceinline__ unsigned short f2b(float f) {
  unsigned int u = __builtin_bit_cast(unsigned int, f);
  return (unsigned short)((u + 0x8000u) >> 16);
}
__device__ __forceinline__ unsigned int cvt_pk_bf16(float lo, float hi) {
  unsigned int r;
  asm("v_cvt_pk_bf16_f32 %0, %1, %2" : "=v"(r) : "v"(lo), "v"(hi));
  return r;
}
__device__ __forceinline__ void async_copy16(void* lds, const void* g) {
  __builtin_amdgcn_global_load_lds((const __attribute__((address_space(1))) void*)g,
                                   (__attribute__((address_space(3))) void*)lds,
                                   16, 0, 0);
}

// raw barrier (no waitcnt drain) + compiler memory fences
#define BARRIER() do { asm volatile("" ::: "memory"); __builtin_amdgcn_s_barrier(); asm volatile("" ::: "memory"); } while (0)
#define LGKM0()   asm volatile("s_waitcnt lgkmcnt(0)" ::: "memory")
#define WAITVM(n) asm volatile("s_waitcnt vmcnt(" #n ")" ::: "memory")
#define MFMA16(d, a, bb) (d) = __builtin_amdgcn_mfma_f32_16x16x32_bf16((a), (bb), (d), 0, 0, 0)

// ---- dtype detector ----
__global__ void detect_mode(const unsigned short* __restrict__ w, int* __restrict__ flags) {
  int t = threadIdx.x;
  int trips = 0;
  for (int i = 0; i < 4; i++) {
    unsigned short u = w[t * 4 + i];
    int e = (u >> 7) & 0xFF;
    if (e >= 161 || (e <= 93 && e != 0)) trips++;
  }
  for (int off = 32; off > 0; off >>= 1) trips += __shfl_down(trips, off);
  if (t == 0) flags[0] = (trips >= 8) ? 1 : 0;  // 1 = fp32 I/O, 0 = bf16
}

// ---- X -> bf16 ----
__global__ __launch_bounds__(256) void convert_x(const void* __restrict__ xin,
                                                 unsigned short* __restrict__ xb,
                                                 const int* __restrict__ flags, int n) {
  int mode = flags[0];
  int i = (blockIdx.x * 256 + threadIdx.x) * 8;
  if (i >= n) return;
  if (mode) {
    const float* f = (const float*)xin;
    us8 o;
#pragma unroll
    for (int j = 0; j < 8; j++) o[j] = f2b(f[i + j]);
    *(us8*)&xb[i] = o;
  } else {
    *(us8*)&xb[i] = *(const us8*)((const unsigned short*)xin + i);
  }
}

// ---- W [R][C] -> bf16 W^T [C][R] ----
__global__ __launch_bounds__(256) void transpose_w(const void* __restrict__ win,
                                                   unsigned short* __restrict__ out,
                                                   const int* __restrict__ flags,
                                                   int R, int C) {
  __shared__ float tile[32][33];
  int mode = flags[0];
  int c0 = blockIdx.x * 32, r0 = blockIdx.y * 32;
  int tx = threadIdx.x & 31, ty = threadIdx.x >> 5;
  if (mode) {
    const float* f = (const float*)win;
    for (int i = ty; i < 32; i += 8) tile[i][tx] = f[(size_t)(r0 + i) * C + c0 + tx];
  } else {
    const unsigned short* bsrc = (const unsigned short*)win;
    for (int i = ty; i < 32; i += 8) tile[i][tx] = b2f(bsrc[(size_t)(r0 + i) * C + c0 + tx]);
  }
  __syncthreads();
  for (int i = ty; i < 32; i += 8) out[(size_t)(c0 + i) * R + r0 + tx] = f2b(tile[tx][i]);
}

#define QSC 0.18033688011112042f   // (1/8) * log2(e)

// ============================================================================
// 8-phase 256x256 QKV GEMM + RoPE + head-major scatter. (unchanged)
// ============================================================================
__global__ __launch_bounds__(512, 2)
void gemm_qkv(const unsigned short* __restrict__ A, const unsigned short* __restrict__ Bt,
              const int* __restrict__ pos_ids,
              unsigned short* __restrict__ qws, unsigned short* __restrict__ kws,
              unsigned short* __restrict__ vt) {
  __shared__ __align__(16) unsigned short sm[65536];  // 128 KiB
  int tid = threadIdx.x, lane = tid & 63, wave = tid >> 6;
  int wm = wave >> 2, wn = wave & 3;           // 2 x 4 waves, wave tile 128x64
  int quad = lane >> 4, l15 = lane & 15;

  int bid = blockIdx.x;                         // 192 blocks, 192 % 8 == 0
  int wg = (bid & 7) * 24 + (bid >> 3);         // XCD-contiguous chunks of 24
  int ty = wg / 12, tx = wg - ty * 12;
  size_t tm0 = (size_t)ty * 256, tn0 = (size_t)tx * 256;

  const unsigned short* Ab = A + tm0 * 2048;
  const unsigned short* Bb = Bt + tn0 * 2048;

  auto UA = [&](int bu, int kh) { return sm + (bu * 2 + kh) * 8192; };
  auto UB = [&](int bu, int kh) { return sm + 32768 + (bu * 2 + kh) * 8192; };

  int c0 = tid, c1 = tid + 512;
  int r0s = c0 >> 2, r1s = c1 >> 2;
  int cc0 = (c0 & 3) ^ ((r0s >> 1) & 3);
  int cc1 = (c1 & 3) ^ ((r1s >> 1) & 3);
  size_t ga0 = (size_t)r0s * 2048 + cc0 * 8;
  size_t ga1 = (size_t)r1s * 2048 + cc1 * 8;

  auto stA = [&](int t, int kh, int bu) {
    const unsigned short* s = Ab + (size_t)t * 64 + kh * 32;
    async_copy16(UA(bu, kh) + c0 * 8, s + ga0);
    async_copy16(UA(bu, kh) + c1 * 8, s + ga1);
  };
  auto stB = [&](int t, int kh, int bu) {
    const unsigned short* s = Bb + (size_t)t * 64 + kh * 32;
    async_copy16(UB(bu, kh) + c0 * 8, s + ga0);
    async_copy16(UB(bu, kh) + c1 * 8, s + ga1);
  };

  int rdoff = l15 * 32 + ((quad << 3) ^ (((l15 >> 1) & 3) << 3));

  f32x4 zero4 = {0.f, 0.f, 0.f, 0.f};
  f32x4 acc[8][4];
#pragma unroll
  for (int mi = 0; mi < 8; mi++)
#pragma unroll
    for (int ni = 0; ni < 4; ni++) acc[mi][ni] = zero4;

  stA(0, 0, 0); stB(0, 0, 0); stA(0, 1, 0); stB(0, 1, 0); stA(1, 0, 1); stB(1, 0, 1);
  WAITVM(8); BARRIER();

#pragma unroll 2
  for (int t = 0; t < 32; ++t) {
    int bu = t & 1, bn = bu ^ 1;
    int t1 = (t + 1 < 32) ? t + 1 : 31;
    int t2 = (t + 2 < 32) ? t + 2 : 31;
    bf16x8 af[8];
    const unsigned short* pA0 = UA(bu, 0) + wm * 4096 + rdoff;
    const unsigned short* pB0 = UB(bu, 0) + wn * 2048 + rdoff;
    const unsigned short* pA1 = UA(bu, 1) + wm * 4096 + rdoff;
    const unsigned short* pB1 = UB(bu, 1) + wn * 2048 + rdoff;

    // p0
#pragma unroll
    for (int mi = 0; mi < 8; mi++) af[mi] = *(const bf16x8*)(pA0 + mi * 512);
    bf16x8 b0 = *(const bf16x8*)pB0;
    bf16x8 b1 = *(const bf16x8*)(pB0 + 512);
    stA(t1, 1, bn);
    BARRIER(); LGKM0();
    __builtin_amdgcn_s_setprio(1);
#pragma unroll
    for (int mi = 0; mi < 8; mi++) { MFMA16(acc[mi][0], af[mi], b0); MFMA16(acc[mi][1], af[mi], b1); }
    __builtin_amdgcn_s_setprio(0);
    BARRIER();

    // p1
    bf16x8 b2 = *(const bf16x8*)(pB0 + 1024);
    bf16x8 b3 = *(const bf16x8*)(pB0 + 1536);
    stB(t1, 1, bn);
    BARRIER(); LGKM0();
    __builtin_amdgcn_s_setprio(1);
#pragma unroll
    for (int mi = 0; mi < 8; mi++) { MFMA16(acc[mi][2], af[mi], b2); MFMA16(acc[mi][3], af[mi], b3); }
    __builtin_amdgcn_s_setprio(0);
    WAITVM(8);
    BARRIER();

    // p2
#pragma unroll
    for (int mi = 0; mi < 8; mi++) af[mi] = *(const bf16x8*)(pA1 + mi * 512);
    b0 = *(const bf16x8*)pB1;
    b1 = *(const bf16x8*)(pB1 + 512);
    stA(t2, 0, bu);
    BARRIER(); LGKM0();
    __builtin_amdgcn_s_setprio(1);
#pragma unroll
    for (int mi = 0; mi < 8; mi++) { MFMA16(acc[mi][0], af[mi], b0); MFMA16(acc[mi][1], af[mi], b1); }
    __builtin_amdgcn_s_setprio(0);
    BARRIER();

    // p3
    b2 = *(const bf16x8*)(pB1 + 1024);
    b3 = *(const bf16x8*)(pB1 + 1536);
    stB(t2, 0, bu);
    BARRIER(); LGKM0();
    __builtin_amdgcn_s_setprio(1);
#pragma unroll
    for (int mi = 0; mi < 8; mi++) { MFMA16(acc[mi][2], af[mi], b2); MFMA16(acc[mi][3], af[mi], b3); }
    __builtin_amdgcn_s_setprio(0);
    WAITVM(8);
    BARRIER();
  }
  WAITVM(0);

  // ---- epilogue: RoPE for Q/K slots, transposed scatter for V ----
  int hs = (int)(tn0 >> 6) + wn;
  if (hs < 40) {
    float sc = (hs < 32) ? QSC : 1.0f;
    unsigned short* dst0 = (hs < 32) ? qws : kws;
    int hh = (hs < 32) ? hs : (hs - 32);
    float invf0 = __expf(-(float)l15 * (9.210340371976184f / 32.0f));
    float invf1 = invf0 * 0.01f;
#pragma unroll
    for (int mi = 0; mi < 8; mi++)
#pragma unroll
      for (int r = 0; r < 4; r++) {
        size_t gr = tm0 + wm * 128 + mi * 16 + quad * 4 + r;
        int bb = (int)(gr >> 11), s = (int)(gr & 2047);
        float tpos = (float)pos_ids[gr];
        unsigned short* row = dst0 + ((size_t)(bb * ((hs < 32) ? DNH : DKVH) + hh) * DS + s) * DHD;
#pragma unroll
        for (int ni = 0; ni < 2; ni++) {
          float x1 = acc[mi][ni][r], x2 = acc[mi][ni + 2][r];
          float ang = tpos * (ni ? invf1 : invf0);
          float sn, cs;
          __sincosf(ang, &sn, &cs);
          int d = ni * 16 + l15;
          row[d]      = f2b((x1 * cs - x2 * sn) * sc);
          row[d + 32] = f2b((x2 * cs + x1 * sn) * sc);
        }
      }
  } else {
    int vh = hs - 40;
    int bb = (int)(tm0 >> 11);
    int s0 = (int)(tm0 & 2047) + wm * 128 + quad * 4;
#pragma unroll
    for (int mi = 0; mi < 8; mi++)
#pragma unroll
      for (int ni = 0; ni < 4; ni++) {
        int d = ni * 16 + l15;
        us4 o4;
#pragma unroll
        for (int r = 0; r < 4; r++) o4[r] = f2b(acc[mi][ni][r]);
        *(us4*)&vt[((size_t)(bb * DKVH + vh) * DHD + d) * DS + s0 + mi * 16] = o4;
      }
  }
}

// ============================================================================
// 8-phase 128x256 out GEMM (unchanged)
// ============================================================================
__global__ __launch_bounds__(512, 2)
void gemm_out(const unsigned short* __restrict__ A, const unsigned short* __restrict__ Bt,
              unsigned short* __restrict__ Cb, float* __restrict__ Cf,
              const int* __restrict__ outmode) {
  __shared__ __align__(16) unsigned short sm[49152];  // 96 KiB
  int tid = threadIdx.x, lane = tid & 63, wave = tid >> 6;
  int wm = wave >> 2, wn = wave & 3;
  int quad = lane >> 4, l15 = lane & 15;

  int bid = blockIdx.x;
  int wg = (bid & 7) * 32 + (bid >> 3);
  int ty = wg >> 3, tx = wg & 7;
  size_t tm0 = (size_t)ty * 128, tn0 = (size_t)tx * 256;

  const unsigned short* Ab = A + tm0 * 2048;
  const unsigned short* Bb = Bt + tn0 * 2048;

  auto UA = [&](int bu, int kh) { return sm + (bu * 2 + kh) * 4096; };
  auto UB = [&](int bu, int kh) { return sm + 16384 + (bu * 2 + kh) * 8192; };

  int c0 = tid, c1 = tid + 512;
  int r0s = c0 >> 2, r1s = c1 >> 2;
  int cc0 = (c0 & 3) ^ ((r0s >> 1) & 3);
  int cc1 = (c1 & 3) ^ ((r1s >> 1) & 3);
  size_t ga0 = (size_t)r0s * 2048 + cc0 * 8;
  size_t ga1 = (size_t)r1s * 2048 + cc1 * 8;

  auto stA = [&](int t, int kh, int bu) {
    const unsigned short* s = Ab + (size_t)t * 64 + kh * 32;
    async_copy16(UA(bu, kh) + c0 * 8, s + ga0);
  };
  auto stB = [&](int t, int kh, int bu) {
    const unsigned short* s = Bb + (size_t)t * 64 + kh * 32;
    async_copy16(UB(bu, kh) + c0 * 8, s + ga0);
    async_copy16(UB(bu, kh) + c1 * 8, s + ga1);
  };

  int rdoff = l15 * 32 + ((quad << 3) ^ (((l15 >> 1) & 3) << 3));

  f32x4 zero4 = {0.f, 0.f, 0.f, 0.f};
  f32x4 acc[4][4];
#pragma unroll
  for (int mi = 0; mi < 4; mi++)
#pragma unroll
    for (int ni = 0; ni < 4; ni++) acc[mi][ni] = zero4;

  stA(0, 0, 0); stB(0, 0, 0); stA(0, 1, 0); stB(0, 1, 0); stA(1, 0, 1); stB(1, 0, 1);
  WAITVM(6); BARRIER();

#pragma unroll 2
  for (int t = 0; t < 32; ++t) {
    int bu = t & 1, bn = bu ^ 1;
    int t1 = (t + 1 < 32) ? t + 1 : 31;
    int t2 = (t + 2 < 32) ? t + 2 : 31;
    bf16x8 af[4];
    const unsigned short* pA0 = UA(bu, 0) + wm * 2048 + rdoff;
    const unsigned short* pB0 = UB(bu, 0) + wn * 2048 + rdoff;
    const unsigned short* pA1 = UA(bu, 1) + wm * 2048 + rdoff;
    const unsigned short* pB1 = UB(bu, 1) + wn * 2048 + rdoff;

    // p0
#pragma unroll
    for (int mi = 0; mi < 4; mi++) af[mi] = *(const bf16x8*)(pA0 + mi * 512);
    bf16x8 b0 = *(const bf16x8*)pB0;
    bf16x8 b1 = *(const bf16x8*)(pB0 + 512);
    stA(t1, 1, bn);
    BARRIER(); LGKM0();
    __builtin_amdgcn_s_setprio(1);
#pragma unroll
    for (int mi = 0; mi < 4; mi++) { MFMA16(acc[mi][0], af[mi], b0); MFMA16(acc[mi][1], af[mi], b1); }
    __builtin_amdgcn_s_setprio(0);
    BARRIER();

    // p1
    bf16x8 b2 = *(const bf16x8*)(pB0 + 1024);
    bf16x8 b3 = *(const bf16x8*)(pB0 + 1536);
    stB(t1, 1, bn);
    BARRIER(); LGKM0();
    __builtin_amdgcn_s_setprio(1);
#pragma unroll
    for (int mi = 0; mi < 4; mi++) { MFMA16(acc[mi][2], af[mi], b2); MFMA16(acc[mi][3], af[mi], b3); }
    __builtin_amdgcn_s_setprio(0);
    WAITVM(6);
    BARRIER();

    // p2
#pragma unroll
    for (int mi = 0; mi < 4; mi++) af[mi] = *(const bf16x8*)(pA1 + mi * 512);
    b0 = *(const bf16x8*)pB1;
    b1 = *(const bf16x8*)(pB1 + 512);
    stA(t2, 0, bu);
    BARRIER(); LGKM0();
    __builtin_amdgcn_s_setprio(1);
#pragma unroll
    for (int mi = 0; mi < 4; mi++) { MFMA16(acc[mi][0], af[mi], b0); MFMA16(acc[mi][1], af[mi], b1); }
    __builtin_amdgcn_s_setprio(0);
    BARRIER();

    // p3
    b2 = *(const bf16x8*)(pB1 + 1024);
    b3 = *(const bf16x8*)(pB1 + 1536);
    stB(t2, 0, bu);
    BARRIER(); LGKM0();
    __builtin_amdgcn_s_setprio(1);
#pragma unroll
    for (int mi = 0; mi < 4; mi++) { MFMA16(acc[mi][2], af[mi], b2); MFMA16(acc[mi][3], af[mi], b3); }
    __builtin_amdgcn_s_setprio(0);
    WAITVM(6);
    BARRIER();
  }
  WAITVM(0);

  int mode = *outmode;
#pragma unroll
  for (int mi = 0; mi < 4; mi++)
#pragma unroll
    for (int ni = 0; ni < 4; ni++)
#pragma unroll
      for (int r = 0; r < 4; r++) {
        size_t gr = tm0 + wm * 64 + mi * 16 + quad * 4 + r;
        size_t gc = tn0 + wn * 64 + ni * 16 + l15;
        float v = acc[mi][ni][r];
        if (mode) Cf[gr * 2048 + gc] = v;
        else      Cb[gr * 2048 + gc] = f2b(v);
      }
}

// ============================================================================
// causal GQA flash attention v3:
//  - K AND V staged via coalesced global_load_lds (v2's per-lane V global loads
//    were 16-line-split + 4x wave-duplicated -> reverted)
//  - both K and V double-buffered; prefetch issued at top of iter; single
//    WAITVM(0)+barrier per tile at the bottom
//  - K and V tiles XOR-swizzled (inverse on global source, forward on ds_read)
//  - lP: stride 64 + 3-bit row-XOR (phys = logical ^ ((l15&7)<<3)) -> even
//    bank spread (was stride-72, 8-way)
//  - defer-max (T13), cvt_pk packing, max3 reduce
//  LDS: 16K (K dbuf) + 16K (V dbuf) + 8K (P) = 40960 B -> 4 blocks/CU
// ============================================================================
__global__ __launch_bounds__(256, 4)
void flash_attn(const unsigned short* __restrict__ q, const unsigned short* __restrict__ k,
                const unsigned short* __restrict__ vt, unsigned short* __restrict__ ctx) {
  __shared__ __align__(16) unsigned short lK[2][2][64 * 32];  // [buf][half] 16 KiB
  __shared__ __align__(16) unsigned short lV[2][2][64 * 32];  // [buf][half] 16 KiB
  __shared__ __align__(16) unsigned short lP[4][16 * 64];     // 8 KiB
  int tid = threadIdx.x, lane = tid & 63, wave = tid >> 6;
  int quad = lane >> 4, l15 = lane & 15;
  int bh = blockIdx.y, b = bh >> 5, h = bh & 31, kvh = h >> 2;
  const unsigned short* qb = q + (size_t)(b * DNH + h) * DS * DHD;
  const unsigned short* kb = k + (size_t)(b * DKVH + kvh) * DS * DHD;
  const unsigned short* vb = vt + (size_t)(b * DKVH + kvh) * DHD * DS;
  unsigned short* lPw = lP[wave];
  int r4 = tid >> 2;
  int cc8 = ((tid & 3) ^ ((r4 >> 1) & 3)) * 8;   // inverse-swizzled source chunk (K,V)
  int swz = ((l15 >> 1) & 3) << 3;               // K/V read-side XOR (shorts)
  int pswz = (l15 & 7) << 3;                     // P row-XOR (shorts)

  f32x4 zero4 = {0.f, 0.f, 0.f, 0.f};
  for (int ph = 0; ph < 2; ph++) {
    int qt = ph ? (31 - blockIdx.x) : blockIdx.x;
    int q0 = qt * 64;
    const unsigned short* qp = qb + (size_t)(q0 + wave * 16 + l15) * DHD + quad * 8;
    bf16x8 qf0 = *(const bf16x8*)qp;
    bf16x8 qf1 = *(const bf16x8*)(qp + 32);
    f32x4 oacc[4];
#pragma unroll
    for (int dj = 0; dj < 4; dj++) oacc[dj] = zero4;
    float mrow = -1e30f, lrow = 0.f;

    int nt = qt + 1;
    // prologue: stage tile 0 -> buf 0 (K and V)
    {
      const unsigned short* sk = kb + (size_t)r4 * DHD + cc8;
      async_copy16(&lK[0][0][tid * 8], sk);
      async_copy16(&lK[0][1][tid * 8], sk + 32);
      const unsigned short* sv = vb + (size_t)r4 * DS + cc8;
      async_copy16(&lV[0][0][tid * 8], sv);
      async_copy16(&lV[0][1][tid * 8], sv + 32);
    }
    WAITVM(0); BARRIER();

    int cur = 0;
    for (int t = 0; t < nt; t++) {
      int kv0 = t * 64;
      // prefetch next K,V tiles into other buffer (issued before compute)
      if (t + 1 < nt) {
        const unsigned short* sk = kb + (size_t)(kv0 + 64 + r4) * DHD + cc8;
        async_copy16(&lK[cur ^ 1][0][tid * 8], sk);
        async_copy16(&lK[cur ^ 1][1][tid * 8], sk + 32);
        const unsigned short* sv = vb + (size_t)r4 * DS + kv0 + 64 + cc8;
        async_copy16(&lV[cur ^ 1][0][tid * 8], sv);
        async_copy16(&lV[cur ^ 1][1][tid * 8], sv + 32);
      }
      // QK^T from swizzled LDS
      f32x4 sacc[4];
#pragma unroll
      for (int nj = 0; nj < 4; nj++) {
        int ro = (nj * 16 + l15) * 32 + ((quad * 8) ^ swz);
        bf16x8 kf0 = *(const bf16x8*)&lK[cur][0][ro];
        bf16x8 kf1 = *(const bf16x8*)&lK[cur][1][ro];
        sacc[nj] = zero4;
        MFMA16(sacc[nj], kf0, qf0);
        MFMA16(sacc[nj], kf1, qf1);
      }
      if (t == nt - 1) {
        int ql = wave * 16 + l15;
#pragma unroll
        for (int nj = 0; nj < 4; nj++)
#pragma unroll
          for (int r = 0; r < 4; r++)
            if (nj * 16 + quad * 4 + r > ql) sacc[nj][r] = -1e30f;
      }
      // row max
      float a0 = fmaxf(fmaxf(sacc[0][0], sacc[0][1]), sacc[0][2]);
      float a1 = fmaxf(fmaxf(sacc[0][3], sacc[1][0]), sacc[1][1]);
      float a2 = fmaxf(fmaxf(sacc[1][2], sacc[1][3]), sacc[2][0]);
      float a3 = fmaxf(fmaxf(sacc[2][1], sacc[2][2]), sacc[2][3]);
      float a4 = fmaxf(fmaxf(sacc[3][0], sacc[3][1]), sacc[3][2]);
      float tm = fmaxf(fmaxf(fmaxf(a0, a1), fmaxf(a2, a3)), fmaxf(a4, sacc[3][3]));
      tm = fmaxf(tm, __shfl_xor(tm, 16));
      tm = fmaxf(tm, __shfl_xor(tm, 32));
      // defer-max: rescale only when running max grew by > 8 (log2 units)
      if (!__all(tm <= mrow + 8.f)) {
        float mn = fmaxf(mrow, tm);
        float alpha = __builtin_amdgcn_exp2f(mrow - mn);
        mrow = mn;
        lrow *= alpha;
#pragma unroll
        for (int dj = 0; dj < 4; dj++)
#pragma unroll
          for (int r = 0; r < 4; r++) oacc[dj][r] *= alpha;
      }
      float rs = 0.f;
#pragma unroll
      for (int nj = 0; nj < 4; nj++)
#pragma unroll
        for (int r = 0; r < 4; r++) {
          float e = __builtin_amdgcn_exp2f(sacc[nj][r] - mrow);
          sacc[nj][r] = e;
          rs += e;
        }
      rs += __shfl_xor(rs, 16);
      rs += __shfl_xor(rs, 32);
      lrow += rs;
      // pack P -> LDS (per-wave, row-XOR swizzled) via cvt_pk
#pragma unroll
      for (int nj = 0; nj < 4; nj++) {
        u32x2 w2;
        w2[0] = cvt_pk_bf16(sacc[nj][0], sacc[nj][1]);
        w2[1] = cvt_pk_bf16(sacc[nj][2], sacc[nj][3]);
        *(u32x2*)&lPw[l15 * 64 + ((nj * 16 + quad * 4) ^ pswz)] = w2;
      }
      bf16x8 pf0 = *(const bf16x8*)&lPw[l15 * 64 + ((quad * 8) ^ pswz)];
      bf16x8 pf1 = *(const bf16x8*)&lPw[l15 * 64 + ((32 + quad * 8) ^ pswz)];
#pragma unroll
      for (int dj = 0; dj < 4; dj++) {
        int ro = (dj * 16 + l15) * 32 + ((quad * 8) ^ swz);
        bf16x8 vf0 = *(const bf16x8*)&lV[cur][0][ro];
        bf16x8 vf1 = *(const bf16x8*)&lV[cur][1][ro];
        MFMA16(oacc[dj], vf0, pf0);
        MFMA16(oacc[dj], vf1, pf1);
      }
      WAITVM(0); BARRIER();   // prefetch was issued ~whole tile earlier
      cur ^= 1;
    }
    float inv = __builtin_amdgcn_rcpf(lrow);
    size_t orow = ((size_t)b * DS + q0 + wave * 16 + l15) * (DNH * DHD) + (size_t)h * DHD;
#pragma unroll
    for (int dj = 0; dj < 4; dj++) {
      u32x2 o2;
      o2[0] = cvt_pk_bf16(oacc[dj][0] * inv, oacc[dj][1] * inv);
      o2[1] = cvt_pk_bf16(oacc[dj][2] * inv, oacc[dj][3] * inv);
      *(u32x2*)&ctx[orow + dj * 16 + quad * 4] = o2;
    }
  }
}

extern "C" void kernel_launch(void* const* d_in, const int* in_sizes, int n_in,
                              void* d_out, int out_size, void* d_ws, size_t ws_size,
                              hipStream_t stream) {
  (void)in_sizes; (void)n_in; (void)out_size; (void)ws_size;
  const void* hs = d_in[0];
  const int* pos = (const int*)d_in[2];
  const void* wq = d_in[3];
  const void* wk = d_in[4];
  const void* wv = d_in[5];
  const void* wo = d_in[6];

  char* ws = (char*)d_ws;
  size_t off = 0;
  auto take = [&](size_t bytes) -> char* {
    char* p = ws + off;
    off += (bytes + 255) & ~(size_t)255;
    return p;
  };
  int* flags            = (int*)take(256);
  unsigned short* xb    = (unsigned short*)take((size_t)DM * DH * 2);
  unsigned short* wtqkv = (unsigned short*)take((size_t)DNQKV * DH * 2);
  unsigned short* wto   = (unsigned short*)take((size_t)DH * DH * 2);
  unsigned short* qws   = (unsigned short*)take((size_t)DB * DNH * DS * DHD * 2);
  unsigned short* kws   = (unsigned short*)take((size_t)DB * DKVH * DS * DHD * 2);
  unsigned short* vtws  = (unsigned short*)take((size_t)DB * DKVH * DS * DHD * 2);
  unsigned short* ctx   = (unsigned short*)take((size_t)DM * DNH * DHD * 2);

  detect_mode<<<1, 64, 0, stream>>>((const unsigned short*)wq, flags);
  convert_x<<<DM * DH / 8 / 256, 256, 0, stream>>>(hs, xb, flags, DM * DH);
  transpose_w<<<dim3(64, 64), 256, 0, stream>>>(wq, wtqkv, flags, 2048, 2048);
  transpose_w<<<dim3(16, 64), 256, 0, stream>>>(wk, wtqkv + (size_t)2048 * 2048, flags, 2048, 512);
  transpose_w<<<dim3(16, 64), 256, 0, stream>>>(wv, wtqkv + (size_t)2560 * 2048, flags, 2048, 512);
  transpose_w<<<dim3(64, 64), 256, 0, stream>>>(wo, wto, flags, 2048, 2048);

  gemm_qkv<<<dim3(192), 512, 0, stream>>>(xb, wtqkv, pos, qws, kws, vtws);

  flash_attn<<<dim3(16, DB * DNH), 256, 0, stream>>>(qws, kws, vtws, ctx);

  gemm_out<<<dim3(256), 512, 0, stream>>>(ctx, wto, (unsigned short*)d_out, (float*)d_out, flags);
}

// Round 5
// 302.118 us; speedup vs baseline: 1.2818x; 1.0549x over previous
//
#include <hip/hip_runtime.h>
#include <hip/hip_bf16.h>

// ---- problem constants ----
#define DB   2
#define DS   2048
#define DH   2048
#define DNH  32
#define DKVH 8
#define DHD  64
#define DM   4096    // B*S
#define DNQKV 3072   // NH*HD + 2*KVH*HD

typedef __attribute__((ext_vector_type(8))) short bf16x8;
typedef __attribute__((ext_vector_type(4))) float f32x4;
typedef __attribute__((ext_vector_type(8))) unsigned short us8;
typedef __attribute__((ext_vector_type(4))) unsigned short us4;
typedef __attribute__((ext_vector_type(2))) unsigned int u32x2;

__device__ __forceinline__ float b2f(unsigned short u) {
  unsigned int x = ((unsigned int)u) << 16;
  return __builtin_bit_cast(float, x);
}
__device__ __forceinline__ unsigned short f2b(float f) {
  unsigned int u = __builtin_bit_cast(unsigned int, f);
  return (unsigned short)((u + 0x8000u) >> 16);
}
__device__ __forceinline__ unsigned int cvt_pk_bf16(float lo, float hi) {
  unsigned int r;
  asm("v_cvt_pk_bf16_f32 %0, %1, %2" : "=v"(r) : "v"(lo), "v"(hi));
  return r;
}
__device__ __forceinline__ void async_copy16(void* lds, const void* g) {
  __builtin_amdgcn_global_load_lds((const __attribute__((address_space(1))) void*)g,
                                   (__attribute__((address_space(3))) void*)lds,
                                   16, 0, 0);
}

// raw barrier (no waitcnt drain) + compiler memory fences
#define BARRIER() do { asm volatile("" ::: "memory"); __builtin_amdgcn_s_barrier(); asm volatile("" ::: "memory"); } while (0)
#define LGKM0()   asm volatile("s_waitcnt lgkmcnt(0)" ::: "memory")
#define WAITVM(n) asm volatile("s_waitcnt vmcnt(" #n ")" ::: "memory")
#define MFMA16(d, a, bb) (d) = __builtin_amdgcn_mfma_f32_16x16x32_bf16((a), (bb), (d), 0, 0, 0)

// ---- inline dtype detector: wave-reduce over first 256 shorts of Wq ----
// bit-identical logic to the old detect_mode kernel (reads shorts [0,256),
// same trip count, same >=8 threshold); deterministic per wave.
__device__ __forceinline__ int detect_inline(const unsigned short* __restrict__ w) {
  int t = threadIdx.x & 63;
  int trips = 0;
#pragma unroll
  for (int i = 0; i < 4; i++) {
    unsigned short u = w[t * 4 + i];
    int e = (u >> 7) & 0xFF;
    if (e >= 161 || (e <= 93 && e != 0)) trips++;
  }
#pragma unroll
  for (int off = 32; off > 0; off >>= 1) trips += __shfl_down(trips, off);
  return __shfl(trips, 0) >= 8;   // 1 = fp32 I/O, 0 = bf16
}

// ============================================================================
// fused preprocessing: one launch.
//  blocks [0,4096)        : X -> bf16 (8 elems/thread)
//  blocks [4096,8192)     : Wq  [2048][2048] -> W^T
//  blocks [8192,9216)     : Wk  [2048][512]  -> W^T
//  blocks [9216,10240)    : Wv  [2048][512]  -> W^T
//  blocks [10240,14336)   : Wo  [2048][2048] -> W^T
// ============================================================================
__global__ __launch_bounds__(256)
void prep(const void* __restrict__ hs, const void* __restrict__ wq,
          const void* __restrict__ wk, const void* __restrict__ wv,
          const void* __restrict__ wo,
          unsigned short* __restrict__ xb, unsigned short* __restrict__ wtqkv,
          unsigned short* __restrict__ wto) {
  __shared__ float tile[32][33];
  int mode = detect_inline((const unsigned short*)wq);
  int bid = blockIdx.x;
  if (bid < 4096) {
    int i = (bid * 256 + threadIdx.x) * 8;
    if (mode) {
      const float* f = (const float*)hs;
      us8 o;
#pragma unroll
      for (int j = 0; j < 8; j++) o[j] = f2b(f[i + j]);
      *(us8*)&xb[i] = o;
    } else {
      *(us8*)&xb[i] = *(const us8*)((const unsigned short*)hs + i);
    }
    return;
  }
  const void* win; unsigned short* out; int C, bx, by;
  if (bid < 8192)       { int l = bid - 4096;  win = wq; out = wtqkv;                         C = 2048; bx = l & 63; by = l >> 6; }
  else if (bid < 9216)  { int l = bid - 8192;  win = wk; out = wtqkv + (size_t)2048 * 2048;   C = 512;  bx = l & 15; by = l >> 4; }
  else if (bid < 10240) { int l = bid - 9216;  win = wv; out = wtqkv + (size_t)2560 * 2048;   C = 512;  bx = l & 15; by = l >> 4; }
  else                  { int l = bid - 10240; win = wo; out = wto;                           C = 2048; bx = l & 63; by = l >> 6; }
  int c0 = bx * 32, r0 = by * 32;
  int tx = threadIdx.x & 31, ty = threadIdx.x >> 5;
  if (mode) {
    const float* f = (const float*)win;
    for (int i = ty; i < 32; i += 8) tile[i][tx] = f[(size_t)(r0 + i) * C + c0 + tx];
  } else {
    const unsigned short* bsrc = (const unsigned short*)win;
    for (int i = ty; i < 32; i += 8) tile[i][tx] = b2f(bsrc[(size_t)(r0 + i) * C + c0 + tx]);
  }
  __syncthreads();
  for (int i = ty; i < 32; i += 8) out[(size_t)(c0 + i) * 2048 + r0 + tx] = f2b(tile[tx][i]);
}

#define QSC 0.18033688011112042f   // (1/8) * log2(e)

// ============================================================================
// 8-phase 256x256 QKV GEMM + RoPE + head-major scatter. (unchanged)
// ============================================================================
__global__ __launch_bounds__(512, 2)
void gemm_qkv(const unsigned short* __restrict__ A, const unsigned short* __restrict__ Bt,
              const int* __restrict__ pos_ids,
              unsigned short* __restrict__ qws, unsigned short* __restrict__ kws,
              unsigned short* __restrict__ vt) {
  __shared__ __align__(16) unsigned short sm[65536];  // 128 KiB
  int tid = threadIdx.x, lane = tid & 63, wave = tid >> 6;
  int wm = wave >> 2, wn = wave & 3;           // 2 x 4 waves, wave tile 128x64
  int quad = lane >> 4, l15 = lane & 15;

  int bid = blockIdx.x;                         // 192 blocks, 192 % 8 == 0
  int wg = (bid & 7) * 24 + (bid >> 3);         // XCD-contiguous chunks of 24
  int ty = wg / 12, tx = wg - ty * 12;
  size_t tm0 = (size_t)ty * 256, tn0 = (size_t)tx * 256;

  const unsigned short* Ab = A + tm0 * 2048;
  const unsigned short* Bb = Bt + tn0 * 2048;

  auto UA = [&](int bu, int kh) { return sm + (bu * 2 + kh) * 8192; };
  auto UB = [&](int bu, int kh) { return sm + 32768 + (bu * 2 + kh) * 8192; };

  int c0 = tid, c1 = tid + 512;
  int r0s = c0 >> 2, r1s = c1 >> 2;
  int cc0 = (c0 & 3) ^ ((r0s >> 1) & 3);
  int cc1 = (c1 & 3) ^ ((r1s >> 1) & 3);
  size_t ga0 = (size_t)r0s * 2048 + cc0 * 8;
  size_t ga1 = (size_t)r1s * 2048 + cc1 * 8;

  auto stA = [&](int t, int kh, int bu) {
    const unsigned short* s = Ab + (size_t)t * 64 + kh * 32;
    async_copy16(UA(bu, kh) + c0 * 8, s + ga0);
    async_copy16(UA(bu, kh) + c1 * 8, s + ga1);
  };
  auto stB = [&](int t, int kh, int bu) {
    const unsigned short* s = Bb + (size_t)t * 64 + kh * 32;
    async_copy16(UB(bu, kh) + c0 * 8, s + ga0);
    async_copy16(UB(bu, kh) + c1 * 8, s + ga1);
  };

  int rdoff = l15 * 32 + ((quad << 3) ^ (((l15 >> 1) & 3) << 3));

  f32x4 zero4 = {0.f, 0.f, 0.f, 0.f};
  f32x4 acc[8][4];
#pragma unroll
  for (int mi = 0; mi < 8; mi++)
#pragma unroll
    for (int ni = 0; ni < 4; ni++) acc[mi][ni] = zero4;

  stA(0, 0, 0); stB(0, 0, 0); stA(0, 1, 0); stB(0, 1, 0); stA(1, 0, 1); stB(1, 0, 1);
  WAITVM(8); BARRIER();

#pragma unroll 2
  for (int t = 0; t < 32; ++t) {
    int bu = t & 1, bn = bu ^ 1;
    int t1 = (t + 1 < 32) ? t + 1 : 31;
    int t2 = (t + 2 < 32) ? t + 2 : 31;
    bf16x8 af[8];
    const unsigned short* pA0 = UA(bu, 0) + wm * 4096 + rdoff;
    const unsigned short* pB0 = UB(bu, 0) + wn * 2048 + rdoff;
    const unsigned short* pA1 = UA(bu, 1) + wm * 4096 + rdoff;
    const unsigned short* pB1 = UB(bu, 1) + wn * 2048 + rdoff;

    // p0
#pragma unroll
    for (int mi = 0; mi < 8; mi++) af[mi] = *(const bf16x8*)(pA0 + mi * 512);
    bf16x8 b0 = *(const bf16x8*)pB0;
    bf16x8 b1 = *(const bf16x8*)(pB0 + 512);
    stA(t1, 1, bn);
    BARRIER(); LGKM0();
    __builtin_amdgcn_s_setprio(1);
#pragma unroll
    for (int mi = 0; mi < 8; mi++) { MFMA16(acc[mi][0], af[mi], b0); MFMA16(acc[mi][1], af[mi], b1); }
    __builtin_amdgcn_s_setprio(0);
    BARRIER();

    // p1
    bf16x8 b2 = *(const bf16x8*)(pB0 + 1024);
    bf16x8 b3 = *(const bf16x8*)(pB0 + 1536);
    stB(t1, 1, bn);
    BARRIER(); LGKM0();
    __builtin_amdgcn_s_setprio(1);
#pragma unroll
    for (int mi = 0; mi < 8; mi++) { MFMA16(acc[mi][2], af[mi], b2); MFMA16(acc[mi][3], af[mi], b3); }
    __builtin_amdgcn_s_setprio(0);
    WAITVM(8);
    BARRIER();

    // p2
#pragma unroll
    for (int mi = 0; mi < 8; mi++) af[mi] = *(const bf16x8*)(pA1 + mi * 512);
    b0 = *(const bf16x8*)pB1;
    b1 = *(const bf16x8*)(pB1 + 512);
    stA(t2, 0, bu);
    BARRIER(); LGKM0();
    __builtin_amdgcn_s_setprio(1);
#pragma unroll
    for (int mi = 0; mi < 8; mi++) { MFMA16(acc[mi][0], af[mi], b0); MFMA16(acc[mi][1], af[mi], b1); }
    __builtin_amdgcn_s_setprio(0);
    BARRIER();

    // p3
    b2 = *(const bf16x8*)(pB1 + 1024);
    b3 = *(const bf16x8*)(pB1 + 1536);
    stB(t2, 0, bu);
    BARRIER(); LGKM0();
    __builtin_amdgcn_s_setprio(1);
#pragma unroll
    for (int mi = 0; mi < 8; mi++) { MFMA16(acc[mi][2], af[mi], b2); MFMA16(acc[mi][3], af[mi], b3); }
    __builtin_amdgcn_s_setprio(0);
    WAITVM(8);
    BARRIER();
  }
  WAITVM(0);

  // ---- epilogue: RoPE for Q/K slots, transposed scatter for V ----
  int hs = (int)(tn0 >> 6) + wn;
  if (hs < 40) {
    float sc = (hs < 32) ? QSC : 1.0f;
    unsigned short* dst0 = (hs < 32) ? qws : kws;
    int hh = (hs < 32) ? hs : (hs - 32);
    float invf0 = __expf(-(float)l15 * (9.210340371976184f / 32.0f));
    float invf1 = invf0 * 0.01f;
#pragma unroll
    for (int mi = 0; mi < 8; mi++)
#pragma unroll
      for (int r = 0; r < 4; r++) {
        size_t gr = tm0 + wm * 128 + mi * 16 + quad * 4 + r;
        int bb = (int)(gr >> 11), s = (int)(gr & 2047);
        float tpos = (float)pos_ids[gr];
        unsigned short* row = dst0 + ((size_t)(bb * ((hs < 32) ? DNH : DKVH) + hh) * DS + s) * DHD;
#pragma unroll
        for (int ni = 0; ni < 2; ni++) {
          float x1 = acc[mi][ni][r], x2 = acc[mi][ni + 2][r];
          float ang = tpos * (ni ? invf1 : invf0);
          float sn, cs;
          __sincosf(ang, &sn, &cs);
          int d = ni * 16 + l15;
          row[d]      = f2b((x1 * cs - x2 * sn) * sc);
          row[d + 32] = f2b((x2 * cs + x1 * sn) * sc);
        }
      }
  } else {
    int vh = hs - 40;
    int bb = (int)(tm0 >> 11);
    int s0 = (int)(tm0 & 2047) + wm * 128 + quad * 4;
#pragma unroll
    for (int mi = 0; mi < 8; mi++)
#pragma unroll
      for (int ni = 0; ni < 4; ni++) {
        int d = ni * 16 + l15;
        us4 o4;
#pragma unroll
        for (int r = 0; r < 4; r++) o4[r] = f2b(acc[mi][ni][r]);
        *(us4*)&vt[((size_t)(bb * DKVH + vh) * DHD + d) * DS + s0 + mi * 16] = o4;
      }
  }
}

// ============================================================================
// 8-phase 128x256 out GEMM (mode detection inlined)
// ============================================================================
__global__ __launch_bounds__(512, 2)
void gemm_out(const unsigned short* __restrict__ A, const unsigned short* __restrict__ Bt,
              unsigned short* __restrict__ Cb, float* __restrict__ Cf,
              const unsigned short* __restrict__ wqdet) {
  __shared__ __align__(16) unsigned short sm[49152];  // 96 KiB
  int tid = threadIdx.x, lane = tid & 63, wave = tid >> 6;
  int wm = wave >> 2, wn = wave & 3;
  int quad = lane >> 4, l15 = lane & 15;

  int bid = blockIdx.x;
  int wg = (bid & 7) * 32 + (bid >> 3);
  int ty = wg >> 3, tx = wg & 7;
  size_t tm0 = (size_t)ty * 128, tn0 = (size_t)tx * 256;

  const unsigned short* Ab = A + tm0 * 2048;
  const unsigned short* Bb = Bt + tn0 * 2048;

  auto UA = [&](int bu, int kh) { return sm + (bu * 2 + kh) * 4096; };
  auto UB = [&](int bu, int kh) { return sm + 16384 + (bu * 2 + kh) * 8192; };

  int c0 = tid, c1 = tid + 512;
  int r0s = c0 >> 2, r1s = c1 >> 2;
  int cc0 = (c0 & 3) ^ ((r0s >> 1) & 3);
  int cc1 = (c1 & 3) ^ ((r1s >> 1) & 3);
  size_t ga0 = (size_t)r0s * 2048 + cc0 * 8;
  size_t ga1 = (size_t)r1s * 2048 + cc1 * 8;

  auto stA = [&](int t, int kh, int bu) {
    const unsigned short* s = Ab + (size_t)t * 64 + kh * 32;
    async_copy16(UA(bu, kh) + c0 * 8, s + ga0);
  };
  auto stB = [&](int t, int kh, int bu) {
    const unsigned short* s = Bb + (size_t)t * 64 + kh * 32;
    async_copy16(UB(bu, kh) + c0 * 8, s + ga0);
    async_copy16(UB(bu, kh) + c1 * 8, s + ga1);
  };

  int rdoff = l15 * 32 + ((quad << 3) ^ (((l15 >> 1) & 3) << 3));

  f32x4 zero4 = {0.f, 0.f, 0.f, 0.f};
  f32x4 acc[4][4];
#pragma unroll
  for (int mi = 0; mi < 4; mi++)
#pragma unroll
    for (int ni = 0; ni < 4; ni++) acc[mi][ni] = zero4;

  stA(0, 0, 0); stB(0, 0, 0); stA(0, 1, 0); stB(0, 1, 0); stA(1, 0, 1); stB(1, 0, 1);
  WAITVM(6); BARRIER();

#pragma unroll 2
  for (int t = 0; t < 32; ++t) {
    int bu = t & 1, bn = bu ^ 1;
    int t1 = (t + 1 < 32) ? t + 1 : 31;
    int t2 = (t + 2 < 32) ? t + 2 : 31;
    bf16x8 af[4];
    const unsigned short* pA0 = UA(bu, 0) + wm * 2048 + rdoff;
    const unsigned short* pB0 = UB(bu, 0) + wn * 2048 + rdoff;
    const unsigned short* pA1 = UA(bu, 1) + wm * 2048 + rdoff;
    const unsigned short* pB1 = UB(bu, 1) + wn * 2048 + rdoff;

    // p0
#pragma unroll
    for (int mi = 0; mi < 4; mi++) af[mi] = *(const bf16x8*)(pA0 + mi * 512);
    bf16x8 b0 = *(const bf16x8*)pB0;
    bf16x8 b1 = *(const bf16x8*)(pB0 + 512);
    stA(t1, 1, bn);
    BARRIER(); LGKM0();
    __builtin_amdgcn_s_setprio(1);
#pragma unroll
    for (int mi = 0; mi < 4; mi++) { MFMA16(acc[mi][0], af[mi], b0); MFMA16(acc[mi][1], af[mi], b1); }
    __builtin_amdgcn_s_setprio(0);
    BARRIER();

    // p1
    bf16x8 b2 = *(const bf16x8*)(pB0 + 1024);
    bf16x8 b3 = *(const bf16x8*)(pB0 + 1536);
    stB(t1, 1, bn);
    BARRIER(); LGKM0();
    __builtin_amdgcn_s_setprio(1);
#pragma unroll
    for (int mi = 0; mi < 4; mi++) { MFMA16(acc[mi][2], af[mi], b2); MFMA16(acc[mi][3], af[mi], b3); }
    __builtin_amdgcn_s_setprio(0);
    WAITVM(6);
    BARRIER();

    // p2
#pragma unroll
    for (int mi = 0; mi < 4; mi++) af[mi] = *(const bf16x8*)(pA1 + mi * 512);
    b0 = *(const bf16x8*)pB1;
    b1 = *(const bf16x8*)(pB1 + 512);
    stA(t2, 0, bu);
    BARRIER(); LGKM0();
    __builtin_amdgcn_s_setprio(1);
#pragma unroll
    for (int mi = 0; mi < 4; mi++) { MFMA16(acc[mi][0], af[mi], b0); MFMA16(acc[mi][1], af[mi], b1); }
    __builtin_amdgcn_s_setprio(0);
    BARRIER();

    // p3
    b2 = *(const bf16x8*)(pB1 + 1024);
    b3 = *(const bf16x8*)(pB1 + 1536);
    stB(t2, 0, bu);
    BARRIER(); LGKM0();
    __builtin_amdgcn_s_setprio(1);
#pragma unroll
    for (int mi = 0; mi < 4; mi++) { MFMA16(acc[mi][2], af[mi], b2); MFMA16(acc[mi][3], af[mi], b3); }
    __builtin_amdgcn_s_setprio(0);
    WAITVM(6);
    BARRIER();
  }
  WAITVM(0);

  int mode = detect_inline(wqdet);
#pragma unroll
  for (int mi = 0; mi < 4; mi++)
#pragma unroll
    for (int ni = 0; ni < 4; ni++)
#pragma unroll
      for (int r = 0; r < 4; r++) {
        size_t gr = tm0 + wm * 64 + mi * 16 + quad * 4 + r;
        size_t gc = tn0 + wn * 64 + ni * 16 + l15;
        float v = acc[mi][ni][r];
        if (mode) Cf[gr * 2048 + gc] = v;
        else      Cb[gr * 2048 + gc] = f2b(v);
      }
}

// ============================================================================
// causal GQA flash attention (round-3 verbatim: online max + defer-max THR=8;
// poison-safe since P <= 2^8 by construction). K/V dbuf staging via
// global_load_lds, XOR swizzles, lP row-XOR, cvt_pk packing.
//  LDS: 40960 B -> 4 blocks/CU
// ============================================================================
__global__ __launch_bounds__(256, 4)
void flash_attn(const unsigned short* __restrict__ q, const unsigned short* __restrict__ k,
                const unsigned short* __restrict__ vt, unsigned short* __restrict__ ctx) {
  __shared__ __align__(16) unsigned short lK[2][2][64 * 32];  // [buf][half] 16 KiB
  __shared__ __align__(16) unsigned short lV[2][2][64 * 32];  // [buf][half] 16 KiB
  __shared__ __align__(16) unsigned short lP[4][16 * 64];     // 8 KiB
  int tid = threadIdx.x, lane = tid & 63, wave = tid >> 6;
  int quad = lane >> 4, l15 = lane & 15;
  int bh = blockIdx.y, b = bh >> 5, h = bh & 31, kvh = h >> 2;
  const unsigned short* qb = q + (size_t)(b * DNH + h) * DS * DHD;
  const unsigned short* kb = k + (size_t)(b * DKVH + kvh) * DS * DHD;
  const unsigned short* vb = vt + (size_t)(b * DKVH + kvh) * DHD * DS;
  unsigned short* lPw = lP[wave];
  int r4 = tid >> 2;
  int cc8 = ((tid & 3) ^ ((r4 >> 1) & 3)) * 8;   // inverse-swizzled source chunk (K,V)
  int swz = ((l15 >> 1) & 3) << 3;               // K/V read-side XOR (shorts)
  int pswz = (l15 & 7) << 3;                     // P row-XOR (shorts)

  f32x4 zero4 = {0.f, 0.f, 0.f, 0.f};
  for (int ph = 0; ph < 2; ph++) {
    int qt = ph ? (31 - blockIdx.x) : blockIdx.x;
    int q0 = qt * 64;
    const unsigned short* qp = qb + (size_t)(q0 + wave * 16 + l15) * DHD + quad * 8;
    bf16x8 qf0 = *(const bf16x8*)qp;
    bf16x8 qf1 = *(const bf16x8*)(qp + 32);
    f32x4 oacc[4];
#pragma unroll
    for (int dj = 0; dj < 4; dj++) oacc[dj] = zero4;
    float mrow = -1e30f, lrow = 0.f;

    int nt = qt + 1;
    // prologue: stage tile 0 -> buf 0 (K and V)
    {
      const unsigned short* sk = kb + (size_t)r4 * DHD + cc8;
      async_copy16(&lK[0][0][tid * 8], sk);
      async_copy16(&lK[0][1][tid * 8], sk + 32);
      const unsigned short* sv = vb + (size_t)r4 * DS + cc8;
      async_copy16(&lV[0][0][tid * 8], sv);
      async_copy16(&lV[0][1][tid * 8], sv + 32);
    }
    WAITVM(0); BARRIER();

    int cur = 0;
    for (int t = 0; t < nt; t++) {
      int kv0 = t * 64;
      // prefetch next K,V tiles into other buffer (issued before compute)
      if (t + 1 < nt) {
        const unsigned short* sk = kb + (size_t)(kv0 + 64 + r4) * DHD + cc8;
        async_copy16(&lK[cur ^ 1][0][tid * 8], sk);
        async_copy16(&lK[cur ^ 1][1][tid * 8], sk + 32);
        const unsigned short* sv = vb + (size_t)r4 * DS + kv0 + 64 + cc8;
        async_copy16(&lV[cur ^ 1][0][tid * 8], sv);
        async_copy16(&lV[cur ^ 1][1][tid * 8], sv + 32);
      }
      // QK^T from swizzled LDS
      f32x4 sacc[4];
#pragma unroll
      for (int nj = 0; nj < 4; nj++) {
        int ro = (nj * 16 + l15) * 32 + ((quad * 8) ^ swz);
        bf16x8 kf0 = *(const bf16x8*)&lK[cur][0][ro];
        bf16x8 kf1 = *(const bf16x8*)&lK[cur][1][ro];
        sacc[nj] = zero4;
        MFMA16(sacc[nj], kf0, qf0);
        MFMA16(sacc[nj], kf1, qf1);
      }
      if (t == nt - 1) {
        int ql = wave * 16 + l15;
#pragma unroll
        for (int nj = 0; nj < 4; nj++)
#pragma unroll
          for (int r = 0; r < 4; r++)
            if (nj * 16 + quad * 4 + r > ql) sacc[nj][r] = -1e30f;
      }
      // row max
      float a0 = fmaxf(fmaxf(sacc[0][0], sacc[0][1]), sacc[0][2]);
      float a1 = fmaxf(fmaxf(sacc[0][3], sacc[1][0]), sacc[1][1]);
      float a2 = fmaxf(fmaxf(sacc[1][2], sacc[1][3]), sacc[2][0]);
      float a3 = fmaxf(fmaxf(sacc[2][1], sacc[2][2]), sacc[2][3]);
      float a4 = fmaxf(fmaxf(sacc[3][0], sacc[3][1]), sacc[3][2]);
      float tm = fmaxf(fmaxf(fmaxf(a0, a1), fmaxf(a2, a3)), fmaxf(a4, sacc[3][3]));
      tm = fmaxf(tm, __shfl_xor(tm, 16));
      tm = fmaxf(tm, __shfl_xor(tm, 32));
      // defer-max: rescale only when running max grew by > 8 (log2 units)
      if (!__all(tm <= mrow + 8.f)) {
        float mn = fmaxf(mrow, tm);
        float alpha = __builtin_amdgcn_exp2f(mrow - mn);
        mrow = mn;
        lrow *= alpha;
#pragma unroll
        for (int dj = 0; dj < 4; dj++)
#pragma unroll
          for (int r = 0; r < 4; r++) oacc[dj][r] *= alpha;
      }
      float rs = 0.f;
#pragma unroll
      for (int nj = 0; nj < 4; nj++)
#pragma unroll
        for (int r = 0; r < 4; r++) {
          float e = __builtin_amdgcn_exp2f(sacc[nj][r] - mrow);
          sacc[nj][r] = e;
          rs += e;
        }
      rs += __shfl_xor(rs, 16);
      rs += __shfl_xor(rs, 32);
      lrow += rs;
      // pack P -> LDS (per-wave, row-XOR swizzled) via cvt_pk
#pragma unroll
      for (int nj = 0; nj < 4; nj++) {
        u32x2 w2;
        w2[0] = cvt_pk_bf16(sacc[nj][0], sacc[nj][1]);
        w2[1] = cvt_pk_bf16(sacc[nj][2], sacc[nj][3]);
        *(u32x2*)&lPw[l15 * 64 + ((nj * 16 + quad * 4) ^ pswz)] = w2;
      }
      bf16x8 pf0 = *(const bf16x8*)&lPw[l15 * 64 + ((quad * 8) ^ pswz)];
      bf16x8 pf1 = *(const bf16x8*)&lPw[l15 * 64 + ((32 + quad * 8) ^ pswz)];
#pragma unroll
      for (int dj = 0; dj < 4; dj++) {
        int ro = (dj * 16 + l15) * 32 + ((quad * 8) ^ swz);
        bf16x8 vf0 = *(const bf16x8*)&lV[cur][0][ro];
        bf16x8 vf1 = *(const bf16x8*)&lV[cur][1][ro];
        MFMA16(oacc[dj], vf0, pf0);
        MFMA16(oacc[dj], vf1, pf1);
      }
      WAITVM(0); BARRIER();   // prefetch was issued ~whole tile earlier
      cur ^= 1;
    }
    float inv = __builtin_amdgcn_rcpf(lrow);
    size_t orow = ((size_t)b * DS + q0 + wave * 16 + l15) * (DNH * DHD) + (size_t)h * DHD;
#pragma unroll
    for (int dj = 0; dj < 4; dj++) {
      u32x2 o2;
      o2[0] = cvt_pk_bf16(oacc[dj][0] * inv, oacc[dj][1] * inv);
      o2[1] = cvt_pk_bf16(oacc[dj][2] * inv, oacc[dj][3] * inv);
      *(u32x2*)&ctx[orow + dj * 16 + quad * 4] = o2;
    }
  }
}

extern "C" void kernel_launch(void* const* d_in, const int* in_sizes, int n_in,
                              void* d_out, int out_size, void* d_ws, size_t ws_size,
                              hipStream_t stream) {
  (void)in_sizes; (void)n_in; (void)out_size; (void)ws_size;
  const void* hs = d_in[0];
  const int* pos = (const int*)d_in[2];
  const void* wq = d_in[3];
  const void* wk = d_in[4];
  const void* wv = d_in[5];
  const void* wo = d_in[6];

  char* ws = (char*)d_ws;
  size_t off = 0;
  auto take = [&](size_t bytes) -> char* {
    char* p = ws + off;
    off += (bytes + 255) & ~(size_t)255;
    return p;
  };
  unsigned short* xb    = (unsigned short*)take((size_t)DM * DH * 2);
  unsigned short* wtqkv = (unsigned short*)take((size_t)DNQKV * DH * 2);
  unsigned short* wto   = (unsigned short*)take((size_t)DH * DH * 2);
  unsigned short* qws   = (unsigned short*)take((size_t)DB * DNH * DS * DHD * 2);
  unsigned short* kws   = (unsigned short*)take((size_t)DB * DKVH * DS * DHD * 2);
  unsigned short* vtws  = (unsigned short*)take((size_t)DB * DKVH * DS * DHD * 2);
  unsigned short* ctx   = (unsigned short*)take((size_t)DM * DNH * DHD * 2);

  prep<<<14336, 256, 0, stream>>>(hs, wq, wk, wv, wo, xb, wtqkv, wto);

  gemm_qkv<<<dim3(192), 512, 0, stream>>>(xb, wtqkv, pos, qws, kws, vtws);

  flash_attn<<<dim3(16, DB * DNH), 256, 0, stream>>>(qws, kws, vtws, ctx);

  gemm_out<<<dim3(256), 512, 0, stream>>>(ctx, wto, (unsigned short*)d_out, (float*)d_out,
                                          (const unsigned short*)wq);
}